// Round 5
// baseline (497.446 us; speedup 1.0000x reference)
//
#include <hip/hip_runtime.h>

// MetaTransformer collapse: per layer,
//   G[b]  = Zx[b,:2047]^T Zx[b,:2047]   (256x256)   gcol = Zx^T zlab
//   V     = G Pcat^T  (256 x 2048 stacked heads);  M = Qcat2 * Vt3^T  (K=2048)
//   mcol  = (1/N) Qsum gcol
//   Z[b] += Zx[b] M[b]  (+ label-col GEMV with mcol)
// All MFMA GEMMs in A*B^T form, row-major bf16 frags. Gram/M use within-wg
// split-K (4 waves x K=512) + LDS reduce -> bf16 direct (no fp32 round-trip).
// 18 dispatches total, every grid >= 256 wgs.

#define NL   4
#define NH   8
#define DD   256
#define NCH  257
#define NTOK 2048
#define NVAL 2047
#define NB   8

typedef short  short8v __attribute__((ext_vector_type(8)));
typedef short  short4v __attribute__((ext_vector_type(4)));
typedef float  f32x4   __attribute__((ext_vector_type(4)));

__device__ __forceinline__ unsigned short f2b(float x) {
  union { float f; unsigned u; } v; v.f = x;
  unsigned u = v.u + 0x7fffu + ((v.u >> 16) & 1u);
  return (unsigned short)(u >> 16);
}
__device__ __forceinline__ float b2f(short s) {
  union { unsigned u; float f; } v; v.u = ((unsigned)(unsigned short)s) << 16;
  return v.f;
}

// ---- MFMA tile helper: one wave computes (NF*16) x (NG*16), K in [k0,k1).
template <int NF, int NG>
__device__ __forceinline__ void mm_tile_t(const short* A, const short* B, int lda, int ldb,
                                          int ar, int bc, int k0, int k1, int lane,
                                          f32x4 (&acc)[NF][NG]) {
  #pragma unroll 2
  for (int kk = k0; kk < k1; kk += 32) {
    const int kc = kk + ((lane >> 4) << 3);
    short8v av[NF], bv[NG];
    #pragma unroll
    for (int f = 0; f < NF; ++f)
      av[f] = *(const short8v*)(A + (size_t)(ar + f * 16 + (lane & 15)) * lda + kc);
    #pragma unroll
    for (int g = 0; g < NG; ++g)
      bv[g] = *(const short8v*)(B + (size_t)(bc + g * 16 + (lane & 15)) * ldb + kc);
    #pragma unroll
    for (int f = 0; f < NF; ++f)
      #pragma unroll
      for (int g = 0; g < NG; ++g)
        acc[f][g] = __builtin_amdgcn_mfma_f32_16x16x32_bf16(av[f], bv[g], acc[f][g], 0, 0, 0);
  }
}

// ---- k_prep: grid 2112. [0,1024): P cast; [1024,2048): Qcat2 permute-cast;
//              [2048,2112): QsumT[l][t][k] = sum_j Q_j[k][t].
__global__ __launch_bounds__(256) void k_prep(const float* __restrict__ ap,
                                              short* __restrict__ Pbf, short* __restrict__ Qcat2,
                                              float* __restrict__ QsumT) {
  __shared__ float lds[64][65];
  const int bx = blockIdx.x, tid = threadIdx.x;
  if (bx < 1024) {
    const f32x4* src = (const f32x4*)ap;
    int q0 = (bx * 256 + tid) * 2;
    #pragma unroll
    for (int u = 0; u < 2; ++u) {
      int q = q0 + u;
      int lj = q >> 14, rc4 = q & 16383;
      f32x4 v = src[(size_t)(lj * 2) * 16384 + rc4];
      short4v o;
      #pragma unroll
      for (int i = 0; i < 4; ++i) o[i] = (short)f2b(v[i]);
      ((short4v*)Pbf)[(size_t)lj * 16384 + rc4] = o;
    }
    return;
  }
  if (bx < 2048) {
    int idx = bx - 1024;
    int l = idx >> 8, k = idx & 255;
    int j = tid >> 5, t0 = (tid & 31) * 8;
    const float* s = ap + (size_t)((l * 8 + j) * 2 + 1) * 65536 + (size_t)k * 256 + t0;
    f32x4 a = *(const f32x4*)s, bq = *(const f32x4*)(s + 4);
    short8v o;
    #pragma unroll
    for (int i = 0; i < 4; ++i) { o[i] = (short)f2b(a[i]); o[4 + i] = (short)f2b(bq[i]); }
    *(short8v*)(Qcat2 + (size_t)(l * 256 + k) * 2048 + j * 256 + t0) = o;
    return;
  }
  int qb = bx - 2048;
  int l = qb >> 4, xx = qb & 15;
  int k0 = (xx >> 2) * 64, t0 = (xx & 3) * 64;
  int c = tid & 63, r = tid >> 6;
  #pragma unroll
  for (int i = 0; i < 16; ++i) {
    int k = r + i * 4;
    float s = 0.f;
    #pragma unroll
    for (int j = 0; j < 8; ++j)
      s += ap[(size_t)((l * 8 + j) * 2 + 1) * 65536 + (size_t)(k0 + k) * 256 + (t0 + c)];
    lds[k][c] = s;
  }
  __syncthreads();
  #pragma unroll
  for (int i = 0; i < 16; ++i) {
    int tl = r + i * 4;
    QsumT[(size_t)l * 65536 + (size_t)(t0 + tl) * 256 + (k0 + c)] = lds[c][tl];
  }
}

// ---- k_zstage: grid 1024. Zin -> Zxbf (natural bf16), Zxt (transposed, m=2047 zeroed), zlab.
__global__ __launch_bounds__(256) void k_zstage(const float* __restrict__ Zin,
                                                short* __restrict__ Zxbf, short* __restrict__ Zxt,
                                                float* __restrict__ zlab) {
  __shared__ float lds[64][65];
  const int tb = blockIdx.x, tid = threadIdx.x;
  const int x = tb & 3, y = (tb >> 2) & 31, b = tb >> 7;
  const int k0 = x * 64, m0 = y * 64;
  const int c = tid & 63, r = tid >> 6;
  #pragma unroll
  for (int i = 0; i < 16; ++i) {
    int mrow = r + i * 4, m = m0 + mrow;
    float v = Zin[((size_t)b * NTOK + m) * NCH + k0 + c];
    lds[mrow][c] = v;
    Zxbf[((size_t)b * NTOK + m) * DD + k0 + c] = (short)f2b(v);
  }
  if (x == 0 && tid < 64) {
    int m = m0 + tid;
    zlab[b * NTOK + m] = (m == NVAL) ? 0.f : Zin[((size_t)b * NTOK + m) * NCH + DD];
  }
  __syncthreads();
  #pragma unroll
  for (int i = 0; i < 16; ++i) {
    int krow = r + i * 4;
    float v = lds[c][krow];
    if (m0 + c == NVAL) v = 0.f;
    Zxt[((size_t)b * DD + k0 + krow) * NTOK + m0 + c] = (short)f2b(v);
  }
}

// ---- k_gram2: grid (33, NB). x<32: 64x32 G-tile, 4 waves x K=512, LDS reduce -> Gbf.
//               x==32: gcol[s] = sum_m Zxbf[m][s]*zlab[m] (coalesced via Zxbf).
__global__ __launch_bounds__(256) void k_gram2(const short* __restrict__ Zxt,
                                               const short* __restrict__ Zxbf,
                                               const float* __restrict__ zlab,
                                               short* __restrict__ Gbf, float* __restrict__ gcol) {
  __shared__ float smem[4 * 64 * 36];
  const int x = blockIdx.x, b = blockIdx.y;
  const int tid = threadIdx.x, lane = tid & 63, w = tid >> 6;
  if (x == 32) {
    float* zl = smem;
    float* part = smem + 2048;
    #pragma unroll
    for (int i = 0; i < 8; ++i) zl[tid + i * 256] = zlab[b * NTOK + tid + i * 256];
    __syncthreads();
    const short* base = Zxbf + (size_t)b * NTOK * DD + lane * 4;
    float p0 = 0.f, p1 = 0.f, p2 = 0.f, p3 = 0.f;
    #pragma unroll 4
    for (int m = w * 512; m < w * 512 + 512; ++m) {
      short4v v = *(const short4v*)(base + (size_t)m * DD);
      float zm = zl[m];
      p0 += b2f(v[0]) * zm; p1 += b2f(v[1]) * zm;
      p2 += b2f(v[2]) * zm; p3 += b2f(v[3]) * zm;
    }
    part[w * 256 + lane * 4 + 0] = p0;
    part[w * 256 + lane * 4 + 1] = p1;
    part[w * 256 + lane * 4 + 2] = p2;
    part[w * 256 + lane * 4 + 3] = p3;
    __syncthreads();
    gcol[b * 256 + tid] = part[tid] + part[256 + tid] + part[512 + tid] + part[768 + tid];
    return;
  }
  const int r0 = (x >> 3) * 64, c0 = (x & 7) * 32;
  const short* A = Zxt + (size_t)b * DD * NTOK;
  f32x4 acc[4][2];
  #pragma unroll
  for (int f = 0; f < 4; ++f) for (int g = 0; g < 2; ++g) for (int i = 0; i < 4; ++i) acc[f][g][i] = 0.f;
  mm_tile_t<4, 2>(A, A, NTOK, NTOK, r0, c0, w * 512, w * 512 + 512, lane, acc);
  #pragma unroll
  for (int f = 0; f < 4; ++f)
    #pragma unroll
    for (int g = 0; g < 2; ++g)
      #pragma unroll
      for (int i = 0; i < 4; ++i)
        smem[(w * 64 + f * 16 + ((lane >> 4) << 2) + i) * 36 + g * 16 + (lane & 15)] = acc[f][g][i];
  __syncthreads();
  const int rl = tid >> 2, cb = (tid & 3) * 8;
  float s[8] = {};
  #pragma unroll
  for (int ww = 0; ww < 4; ++ww) {
    const float* pp = smem + (ww * 64 + rl) * 36 + cb;
    f32x4 a = *(const f32x4*)pp, bq = *(const f32x4*)(pp + 4);
    #pragma unroll
    for (int i = 0; i < 4; ++i) { s[i] += a[i]; s[4 + i] += bq[i]; }
  }
  short8v o;
  #pragma unroll
  for (int i = 0; i < 8; ++i) o[i] = (short)f2b(s[i]);
  *(short8v*)(Gbf + (size_t)b * 65536 + (size_t)(r0 + rl) * 256 + c0 + cb) = o;
}

// ---- k_pv: grid (33, NB). x<32: V2[t][jc] = (G Pcat^T), 128x128 tile, write Vt3[b][c][j*256+t].
//            x==32: mcol = invN * QsumT gcol.
__global__ __launch_bounds__(256) void k_pv(const short* __restrict__ Gbf, const short* __restrict__ Pbf,
                                            const float* __restrict__ QsumT, const float* __restrict__ gcol,
                                            short* __restrict__ Vt3, float* __restrict__ mcol, int layer) {
  const int x = blockIdx.x, b = blockIdx.y;
  const int tid = threadIdx.x, lane = tid & 63, wid = tid >> 6;
  if (x == 32) {
    __shared__ float gs[256];
    gs[tid] = gcol[b * 256 + tid];
    __syncthreads();
    float s = 0.f;
    for (int t = 0; t < 256; ++t) s += QsumT[(size_t)layer * 65536 + (size_t)t * 256 + tid] * gs[t];
    mcol[b * 256 + tid] = s * (1.0f / (float)NVAL);
    return;
  }
  const int wr = wid >> 1, wc = wid & 1;
  const int ar = (x & 1) * 128 + wr * 64;        // t rows
  const int bc = (x >> 1) * 128 + wc * 64;       // jc rows
  const short* A = Gbf + (size_t)b * 65536;
  const short* B = Pbf + (size_t)layer * 8 * 65536;
  f32x4 acc[4][4];
  #pragma unroll
  for (int f = 0; f < 4; ++f) for (int g = 0; g < 4; ++g) for (int i = 0; i < 4; ++i) acc[f][g][i] = 0.f;
  mm_tile_t<4, 4>(A, B, 256, 256, ar, bc, 0, 256, lane, acc);
  short* out = Vt3 + (size_t)b * 524288;
  #pragma unroll
  for (int f = 0; f < 4; ++f) {
    const int t0 = ar + f * 16 + ((lane >> 4) << 2);
    #pragma unroll
    for (int g = 0; g < 4; ++g) {
      const int jc = bc + g * 16 + (lane & 15);
      const int j = jc >> 8, c = jc & 255;
      short4v p;
      #pragma unroll
      for (int i = 0; i < 4; ++i) p[i] = (short)f2b(acc[f][g][i]);
      *(short4v*)(out + (size_t)c * 2048 + j * 256 + t0) = p;
    }
  }
}

// ---- k_qm2: grid (32, NB). 64(k)x32(c) M-tile, 4 waves x K=512 over jt, LDS reduce,
//             invN-scale, write Mt[b][c][k] (transposed) bf16.
__global__ __launch_bounds__(256) void k_qm2(const short* __restrict__ Qcat2, const short* __restrict__ Vt3,
                                             short* __restrict__ Mt, int layer) {
  __shared__ float lds[4 * 64 * 33];
  const int x = blockIdx.x, b = blockIdx.y;
  const int tid = threadIdx.x, lane = tid & 63, w = tid >> 6;
  const int r0 = (x >> 3) * 64, c0 = (x & 7) * 32;
  const short* A = Qcat2 + (size_t)layer * 256 * 2048;
  const short* B = Vt3 + (size_t)b * 524288;
  f32x4 acc[4][2];
  #pragma unroll
  for (int f = 0; f < 4; ++f) for (int g = 0; g < 2; ++g) for (int i = 0; i < 4; ++i) acc[f][g][i] = 0.f;
  mm_tile_t<4, 2>(A, B, 2048, 2048, r0, c0, w * 512, w * 512 + 512, lane, acc);
  #pragma unroll
  for (int f = 0; f < 4; ++f)
    #pragma unroll
    for (int g = 0; g < 2; ++g)
      #pragma unroll
      for (int i = 0; i < 4; ++i)
        lds[(w * 64 + f * 16 + ((lane >> 4) << 2) + i) * 33 + g * 16 + (lane & 15)] = acc[f][g][i];
  __syncthreads();
  const float invN = 1.0f / (float)NVAL;
  const int cl = tid >> 3, kb = (tid & 7) * 8;
  float s[8] = {};
  #pragma unroll
  for (int ww = 0; ww < 4; ++ww)
    #pragma unroll
    for (int kk = 0; kk < 8; ++kk)
      s[kk] += lds[(ww * 64 + kb + kk) * 33 + cl];
  short8v o;
  #pragma unroll
  for (int kk = 0; kk < 8; ++kk) o[kk] = (short)f2b(s[kk] * invN);
  *(short8v*)(Mt + (size_t)b * 65536 + (size_t)(c0 + cl) * 256 + r0 + kb) = o;
}

// ---- k_apply: Z = Zsrc + Zx M (+ label GEMV); fused next-layer staging.
//      Zxt written via LDS transpose (coalesced 256B rows).
__global__ __launch_bounds__(256) void k_apply(const float* __restrict__ Zsrc, float* __restrict__ Z,
                                               const short* __restrict__ Zxbf_in, const short* __restrict__ Mt,
                                               const float* __restrict__ mcol,
                                               short* __restrict__ Zxbf_out, short* __restrict__ Zxt_out,
                                               float* __restrict__ zlab_out, int wnext) {
  __shared__ short ldsT[128][136];
  const int tid = threadIdx.x, lane = tid & 63, wid = tid >> 6;
  const int wr = wid >> 1, wc = wid & 1;
  const int b = blockIdx.z;
  const int ar_wg = blockIdx.y * 128, bc_wg = blockIdx.x * 128;
  const int ar = ar_wg + wr * 64;                 // n rows
  const int bc = bc_wg + wc * 64;                 // c rows
  const short* A = Zxbf_in + (size_t)b * NTOK * DD;
  const short* B = Mt + (size_t)b * 65536;
  const bool gemv = (blockIdx.x == 0 && wc == 0);
  f32x4 acc[4][4];
  #pragma unroll
  for (int f = 0; f < 4; ++f) for (int g = 0; g < 4; ++g) for (int i = 0; i < 4; ++i) acc[f][g][i] = 0.f;
  float s[4] = {0.f, 0.f, 0.f, 0.f};
  #pragma unroll 2
  for (int kk = 0; kk < 256; kk += 32) {
    const int kc = kk + ((lane >> 4) << 3);
    short8v av[4], bv[4];
    #pragma unroll
    for (int f = 0; f < 4; ++f)
      av[f] = *(const short8v*)(A + (size_t)(ar + f * 16 + (lane & 15)) * DD + kc);
    #pragma unroll
    for (int g = 0; g < 4; ++g)
      bv[g] = *(const short8v*)(B + (size_t)(bc + g * 16 + (lane & 15)) * 256 + kc);
    if (gemv) {
      const float* mp = mcol + b * 256 + kc;
      f32x4 m0 = *(const f32x4*)mp, m1 = *(const f32x4*)(mp + 4);
      #pragma unroll
      for (int f = 0; f < 4; ++f) {
        #pragma unroll
        for (int q = 0; q < 4; ++q) {
          s[f] += b2f(av[f][q]) * m0[q];
          s[f] += b2f(av[f][4 + q]) * m1[q];
        }
      }
    }
    #pragma unroll
    for (int f = 0; f < 4; ++f)
      #pragma unroll
      for (int g = 0; g < 4; ++g)
        acc[f][g] = __builtin_amdgcn_mfma_f32_16x16x32_bf16(av[f], bv[g], acc[f][g], 0, 0, 0);
  }
  #pragma unroll
  for (int f = 0; f < 4; ++f) {
    const int nb = ar + f * 16 + ((lane >> 4) << 2);
    #pragma unroll
    for (int g = 0; g < 4; ++g) {
      const int c = bc + g * 16 + (lane & 15);
      const int cl = c - bc_wg;
      #pragma unroll
      for (int i = 0; i < 4; ++i) {
        size_t idx = ((size_t)b * NTOK + nb + i) * NCH + c;
        float nv = Zsrc[idx] + acc[f][g][i];
        Z[idx] = nv;
        unsigned short bvv = f2b(nv);
        if (wnext) {
          Zxbf_out[((size_t)b * NTOK + nb + i) * DD + c] = (short)bvv;
          ldsT[cl][nb - ar_wg + i] = (nb + i == NVAL) ? (short)0 : (short)bvv;
        }
      }
    }
  }
  if (gemv) {
    #pragma unroll
    for (int f = 0; f < 4; ++f) {
      float t = s[f];
      t += __shfl_xor(t, 16);
      t += __shfl_xor(t, 32);
      if ((lane >> 4) == 0) {
        int n = ar + f * 16 + (lane & 15);
        size_t idx = ((size_t)b * NTOK + n) * NCH + DD;
        float nv = Zsrc[idx] + t;
        Z[idx] = nv;
        if (wnext) zlab_out[b * NTOK + n] = (n == NVAL) ? 0.f : nv;
      }
    }
  }
  if (wnext) {
    __syncthreads();
    const int n0 = (tid & 15) * 8, cr0 = (tid >> 4) * 8;
    #pragma unroll
    for (int r = 0; r < 8; ++r) {
      short8v v = *(const short8v*)&ldsT[cr0 + r][n0];
      *(short8v*)(Zxt_out + ((size_t)b * DD + bc_wg + cr0 + r) * NTOK + ar_wg + n0) = v;
    }
  }
}

// ================= fallback (round-1 fp32 path, used if ws too small) =================
__global__ __launch_bounds__(256) void gram_kernel(const float* __restrict__ Z, float* __restrict__ G) {
  __shared__ float As[32][64];
  __shared__ float Bs[32][65];
  const int c0 = blockIdx.x * 64, k0 = blockIdx.y * 64, b = blockIdx.z;
  const int tid = threadIdx.x, tx = tid & 15, ty = tid >> 4;
  const float* Zb = Z + (size_t)b * NTOK * NCH;
  float acc[4][4] = {};
  for (int m0 = 0; m0 < NVAL; m0 += 32) {
    #pragma unroll
    for (int l = 0; l < 8; ++l) {
      int e = tid + l * 256, mm = e >> 6, kk = e & 63, m = m0 + mm;
      As[mm][kk] = (m < NVAL) ? Zb[(size_t)m * NCH + (k0 + kk)] : 0.f;
    }
    #pragma unroll
    for (int l = 0; l < 8; ++l) {
      int e = tid + l * 256, mm = e >> 6, cc = e & 63, m = m0 + mm, c = c0 + cc;
      Bs[mm][cc] = (m < NVAL && c < NCH) ? Zb[(size_t)m * NCH + c] : 0.f;
    }
    __syncthreads();
    #pragma unroll
    for (int mm = 0; mm < 32; ++mm) {
      float a[4], bb[4];
      #pragma unroll
      for (int i = 0; i < 4; ++i) a[i] = As[mm][ty * 4 + i];
      #pragma unroll
      for (int j = 0; j < 4; ++j) bb[j] = Bs[mm][tx * 4 + j];
      #pragma unroll
      for (int i = 0; i < 4; ++i)
        #pragma unroll
        for (int j = 0; j < 4; ++j) acc[i][j] += a[i] * bb[j];
    }
    __syncthreads();
  }
  float* Gb = G + (size_t)b * DD * NCH;
  #pragma unroll
  for (int i = 0; i < 4; ++i) {
    int k = k0 + ty * 4 + i;
    #pragma unroll
    for (int j = 0; j < 4; ++j) {
      int c = c0 + tx * 4 + j;
      if (c < NCH) Gb[(size_t)k * NCH + c] = acc[i][j];
    }
  }
}
__global__ __launch_bounds__(256) void pmul_kernel(const float* __restrict__ G, const float* __restrict__ allparam,
                                                   float* __restrict__ U, int layer, int j0, int JB) {
  __shared__ float As[64][33];
  __shared__ float Bs[64][33];
  const int c0 = blockIdx.x * 64, k0 = blockIdx.y * 64;
  const int b = blockIdx.z / JB, jj = blockIdx.z % JB, j = j0 + jj;
  const int tid = threadIdx.x, tx = tid & 15, ty = tid >> 4;
  const float* P = allparam + ((size_t)((layer * NH + j) * 2 + 0)) * DD * DD;
  const float* Gb = G + (size_t)b * DD * NCH;
  float acc[4][4] = {};
  for (int t0 = 0; t0 < DD; t0 += 32) {
    #pragma unroll
    for (int l = 0; l < 8; ++l) {
      int e = tid + l * 256, kk = e >> 5, tt = e & 31;
      As[kk][tt] = Gb[(size_t)(k0 + kk) * NCH + (t0 + tt)];
    }
    #pragma unroll
    for (int l = 0; l < 8; ++l) {
      int e = tid + l * 256, cc = e >> 5, tt = e & 31, c = c0 + cc;
      Bs[cc][tt] = (c < DD) ? P[(size_t)c * DD + (t0 + tt)] : 0.f;
    }
    __syncthreads();
    #pragma unroll
    for (int tt = 0; tt < 32; ++tt) {
      float a[4], bb[4];
      #pragma unroll
      for (int i = 0; i < 4; ++i) a[i] = As[ty * 4 + i][tt];
      #pragma unroll
      for (int j2 = 0; j2 < 4; ++j2) bb[j2] = Bs[tx * 4 + j2][tt];
      #pragma unroll
      for (int i = 0; i < 4; ++i)
        #pragma unroll
        for (int j2 = 0; j2 < 4; ++j2) acc[i][j2] += a[i] * bb[j2];
    }
    __syncthreads();
  }
  float* Us = U + ((size_t)(b * JB + jj)) * DD * NCH;
  #pragma unroll
  for (int i = 0; i < 4; ++i) {
    int k = k0 + ty * 4 + i;
    #pragma unroll
    for (int j2 = 0; j2 < 4; ++j2) {
      int c = c0 + tx * 4 + j2;
      if (c < DD)       Us[(size_t)k * NCH + c] = acc[i][j2];
      else if (c == DD) Us[(size_t)k * NCH + c] = Gb[(size_t)k * NCH + DD];
    }
  }
}
__global__ __launch_bounds__(256) void qmul_kernel(const float* __restrict__ U, const float* __restrict__ allparam,
                                                   float* __restrict__ M, int layer, int j0, int jcount, int JB,
                                                   int accumulate) {
  __shared__ float As[64][33];
  __shared__ float Bs[32][65];
  const int c0 = blockIdx.x * 64, k0 = blockIdx.y * 64, b = blockIdx.z;
  const int tid = threadIdx.x, tx = tid & 15, ty = tid >> 4;
  const float invN = 1.0f / (float)NVAL;
  float acc[4][4] = {};
  for (int jj = 0; jj < jcount; ++jj) {
    const float* Q = allparam + ((size_t)((layer * NH + (j0 + jj)) * 2 + 1)) * DD * DD;
    const float* Ub = U + ((size_t)(b * JB + jj)) * DD * NCH;
    for (int t0 = 0; t0 < DD; t0 += 32) {
      #pragma unroll
      for (int l = 0; l < 8; ++l) {
        int e = tid + l * 256, kk = e >> 5, tt = e & 31;
        As[kk][tt] = Q[(size_t)(k0 + kk) * DD + (t0 + tt)];
      }
      #pragma unroll
      for (int l = 0; l < 8; ++l) {
        int e = tid + l * 256, tt = e >> 6, cc = e & 63, c = c0 + cc;
        Bs[tt][cc] = (c < NCH) ? Ub[(size_t)(t0 + tt) * NCH + c] : 0.f;
      }
      __syncthreads();
      #pragma unroll
      for (int tt = 0; tt < 32; ++tt) {
        float a[4], bb[4];
        #pragma unroll
        for (int i = 0; i < 4; ++i) a[i] = As[ty * 4 + i][tt];
        #pragma unroll
        for (int j2 = 0; j2 < 4; ++j2) bb[j2] = Bs[tt][tx * 4 + j2];
        #pragma unroll
        for (int i = 0; i < 4; ++i)
          #pragma unroll
          for (int j2 = 0; j2 < 4; ++j2) acc[i][j2] += a[i] * bb[j2];
      }
      __syncthreads();
    }
  }
  #pragma unroll
  for (int i = 0; i < 4; ++i) {
    int k = k0 + ty * 4 + i;
    #pragma unroll
    for (int j2 = 0; j2 < 4; ++j2) {
      int c = c0 + tx * 4 + j2;
      if (c < NCH) {
        size_t idx = ((size_t)b * DD + k) * NCH + c;
        float v = invN * acc[i][j2];
        M[idx] = accumulate ? (M[idx] + v) : v;
      }
    }
  }
}
__global__ __launch_bounds__(256) void apply_kernel(float* __restrict__ Z, const float* __restrict__ M) {
  __shared__ float Zs[8][256];
  const int b = blockIdx.y, n0 = blockIdx.x * 8;
  float* Zb = Z + (size_t)b * NTOK * NCH;
  const float* Mb = M + (size_t)b * DD * NCH;
  const int tid = threadIdx.x;
  #pragma unroll
  for (int l = 0; l < 8; ++l) {
    int e = tid + l * 256, r = e >> 8, k = e & 255;
    Zs[r][k] = Zb[(size_t)(n0 + r) * NCH + k];
  }
  __syncthreads();
  const int r = tid >> 5, cbase = tid & 31;
  float acc[9] = {};
  #pragma unroll 4
  for (int k = 0; k < 256; ++k) {
    float z = Zs[r][k];
    const float* Mrow = Mb + (size_t)k * NCH;
    #pragma unroll
    for (int ii = 0; ii < 8; ++ii) acc[ii] += z * Mrow[cbase + ii * 32];
    if (cbase == 0) acc[8] += z * Mrow[256];
  }
  #pragma unroll
  for (int ii = 0; ii < 8; ++ii)
    Zb[(size_t)(n0 + r) * NCH + cbase + ii * 32] += acc[ii];
  if (cbase == 0) Zb[(size_t)(n0 + r) * NCH + 256] += acc[8];
}

// =====================================================================================
extern "C" void kernel_launch(void* const* d_in, const int* in_sizes, int n_in,
                              void* d_out, int out_size, void* d_ws, size_t ws_size,
                              hipStream_t stream) {
  const float* Zin      = (const float*)d_in[0];
  const float* allparam = (const float*)d_in[1];
  float* Z = (float*)d_out;

  // ws layout (bytes)
  const size_t o_zx0  = 0;                         // bf16 [8][2048][256]   8,388,608 (ping)
  const size_t o_zx1  = o_zx0  + 8388608;          // bf16                  8,388,608 (pong)
  const size_t o_zxt  = o_zx1  + 8388608;          // bf16 [8][256][2048]   8,388,608
  const size_t o_gbf  = o_zxt  + 8388608;          // bf16 [8][256][256]    1,048,576
  const size_t o_vt   = o_gbf  + 1048576;          // bf16 [8][256][2048]   8,388,608 (Vt3)
  const size_t o_mt   = o_vt   + 8388608;          // bf16 [8][256][256]    1,048,576
  const size_t o_pbf  = o_mt   + 1048576;          // bf16 [4][8][256][256] 4,194,304
  const size_t o_qc2  = o_pbf  + 4194304;          // bf16 [4][256][2048]   4,194,304 (Qcat2)
  const size_t o_qsum = o_qc2  + 4194304;          // f32  [4][256][256]    1,048,576
  const size_t o_gcol = o_qsum + 1048576;          // f32  [8][256]         8,192
  const size_t o_mcol = o_gcol + 8192;             // f32  [8][256]         8,192
  const size_t o_zlab = o_mcol + 8192;             // f32  [8][2048]        65,536
  const size_t NEED   = o_zlab + 65536;

  if (ws_size >= NEED) {
    char* wsb = (char*)d_ws;
    short* Zx[2]   = { (short*)(wsb + o_zx0), (short*)(wsb + o_zx1) };
    short* Zxt     = (short*)(wsb + o_zxt);
    short* Gbf     = (short*)(wsb + o_gbf);
    short* Vt3     = (short*)(wsb + o_vt);
    short* Mt      = (short*)(wsb + o_mt);
    short* Pbf     = (short*)(wsb + o_pbf);
    short* Qcat2   = (short*)(wsb + o_qc2);
    float* QsumT   = (float*)(wsb + o_qsum);
    float* gcol    = (float*)(wsb + o_gcol);
    float* mcol    = (float*)(wsb + o_mcol);
    float* zlab    = (float*)(wsb + o_zlab);

    k_prep<<<dim3(2112), dim3(256), 0, stream>>>(allparam, Pbf, Qcat2, QsumT);
    k_zstage<<<dim3(1024), dim3(256), 0, stream>>>(Zin, Zx[0], Zxt, zlab);

    for (int layer = 0; layer < NL; ++layer) {
      const int cur = layer & 1;
      const int wnext = (layer < NL - 1) ? 1 : 0;
      const float* Zsrc = (layer == 0) ? Zin : Z;
      k_gram2<<<dim3(33, NB), dim3(256), 0, stream>>>(Zxt, Zx[cur], zlab, Gbf, gcol);
      k_pv<<<dim3(33, NB), dim3(256), 0, stream>>>(Gbf, Pbf, QsumT, gcol, Vt3, mcol, layer);
      k_qm2<<<dim3(32, NB), dim3(256), 0, stream>>>(Qcat2, Vt3, Mt, layer);
      k_apply<<<dim3(2, 16, NB), dim3(256), 0, stream>>>(Zsrc, Z, Zx[cur], Mt, mcol,
                                                         Zx[cur ^ 1], Zxt, zlab, wnext);
    }
    return;
  }

  // -------- fallback: round-1 fp32 path --------
  const size_t zbytes = (size_t)NB * NTOK * NCH * sizeof(float);
  hipMemcpyAsync(Z, Zin, zbytes, hipMemcpyDeviceToDevice, stream);
  const size_t Gn = (size_t)NB * DD * NCH;
  float* ws   = (float*)d_ws;
  float* Gbuf = ws;
  float* Mbuf = ws + Gn;
  float* Ubuf = ws + 2 * Gn;
  const int JB = (ws_size >= (size_t)(2 + 8) * Gn * sizeof(float)) ? 8 : 1;
  dim3 blk(256);
  for (int layer = 0; layer < NL; ++layer) {
    gram_kernel<<<dim3(5, 4, NB), blk, 0, stream>>>(Z, Gbuf);
    for (int j0 = 0; j0 < NH; j0 += JB) {
      pmul_kernel<<<dim3(5, 4, NB * JB), blk, 0, stream>>>(Gbuf, allparam, Ubuf, layer, j0, JB);
      qmul_kernel<<<dim3(5, 4, NB), blk, 0, stream>>>(Ubuf, allparam, Mbuf, layer, j0, JB, JB,
                                                      (j0 == 0) ? 0 : 1);
    }
    apply_kernel<<<dim3(NTOK / 8, NB), blk, 0, stream>>>(Z, Mbuf);
  }
}

// Round 6
// 437.445 us; speedup vs baseline: 1.1372x; 1.1372x over previous
//
#include <hip/hip_runtime.h>

// MetaTransformer collapse: per layer,
//   G[b]  = Zx[b,:2047]^T Zx[b,:2047]   (256x256)   gcol = Zx^T zlab
//   V     = G Pcat^T  (256 x 2048 stacked heads);  M^T = Vt3 Qcat2^T  (K=2048)
//   mcol  = (1/N) Qsum gcol
//   Z[b] += Zx[b] M[b]  (+ label-col GEMV with mcol)
// All MFMA GEMMs A*B^T, row-major bf16 frags. Wide grids (>=512 wgs) via
// cross-wg split-K with fp32 partials + thread-linear reduces. XCD-aware
// b = blockIdx&7 co-location keeps each batch's tensors in one XCD L2.

#define NL   4
#define NH   8
#define DD   256
#define NCH  257
#define NTOK 2048
#define NVAL 2047
#define NB   8

typedef short  short8v __attribute__((ext_vector_type(8)));
typedef short  short4v __attribute__((ext_vector_type(4)));
typedef float  f32x4   __attribute__((ext_vector_type(4)));

__device__ __forceinline__ unsigned short f2b(float x) {
  union { float f; unsigned u; } v; v.f = x;
  unsigned u = v.u + 0x7fffu + ((v.u >> 16) & 1u);
  return (unsigned short)(u >> 16);
}
__device__ __forceinline__ float b2f(short s) {
  union { unsigned u; float f; } v; v.u = ((unsigned)(unsigned short)s) << 16;
  return v.f;
}

// ---- MFMA tile helper: one wave computes (NF*16) x (NG*16), K in [k0,k1).
template <int NF, int NG>
__device__ __forceinline__ void mm_tile_t(const short* A, const short* B, int lda, int ldb,
                                          int ar, int bc, int k0, int k1, int lane,
                                          f32x4 (&acc)[NF][NG]) {
  #pragma unroll 2
  for (int kk = k0; kk < k1; kk += 32) {
    const int kc = kk + ((lane >> 4) << 3);
    short8v av[NF], bv[NG];
    #pragma unroll
    for (int f = 0; f < NF; ++f)
      av[f] = *(const short8v*)(A + (size_t)(ar + f * 16 + (lane & 15)) * lda + kc);
    #pragma unroll
    for (int g = 0; g < NG; ++g)
      bv[g] = *(const short8v*)(B + (size_t)(bc + g * 16 + (lane & 15)) * ldb + kc);
    #pragma unroll
    for (int f = 0; f < NF; ++f)
      #pragma unroll
      for (int g = 0; g < NG; ++g)
        acc[f][g] = __builtin_amdgcn_mfma_f32_16x16x32_bf16(av[f], bv[g], acc[f][g], 0, 0, 0);
  }
}

// ---- k_prep: grid 2112. [0,1024): P cast; [1024,2048): Qcat2 permute-cast;
//              [2048,2112): QsumT[l][t][k] = sum_j Q_j[k][t].
__global__ __launch_bounds__(256) void k_prep(const float* __restrict__ ap,
                                              short* __restrict__ Pbf, short* __restrict__ Qcat2,
                                              float* __restrict__ QsumT) {
  __shared__ float lds[64][65];
  const int bx = blockIdx.x, tid = threadIdx.x;
  if (bx < 1024) {
    const f32x4* src = (const f32x4*)ap;
    int q0 = (bx * 256 + tid) * 2;
    #pragma unroll
    for (int u = 0; u < 2; ++u) {
      int q = q0 + u;
      int lj = q >> 14, rc4 = q & 16383;
      f32x4 v = src[(size_t)(lj * 2) * 16384 + rc4];
      short4v o;
      #pragma unroll
      for (int i = 0; i < 4; ++i) o[i] = (short)f2b(v[i]);
      ((short4v*)Pbf)[(size_t)lj * 16384 + rc4] = o;
    }
    return;
  }
  if (bx < 2048) {
    int idx = bx - 1024;
    int l = idx >> 8, k = idx & 255;
    int j = tid >> 5, t0 = (tid & 31) * 8;
    const float* s = ap + (size_t)((l * 8 + j) * 2 + 1) * 65536 + (size_t)k * 256 + t0;
    f32x4 a = *(const f32x4*)s, bq = *(const f32x4*)(s + 4);
    short8v o;
    #pragma unroll
    for (int i = 0; i < 4; ++i) { o[i] = (short)f2b(a[i]); o[4 + i] = (short)f2b(bq[i]); }
    *(short8v*)(Qcat2 + (size_t)(l * 256 + k) * 2048 + j * 256 + t0) = o;
    return;
  }
  int qb = bx - 2048;
  int l = qb >> 4, xx = qb & 15;
  int k0 = (xx >> 2) * 64, t0 = (xx & 3) * 64;
  int c = tid & 63, r = tid >> 6;
  #pragma unroll
  for (int i = 0; i < 16; ++i) {
    int k = r + i * 4;
    float s = 0.f;
    #pragma unroll
    for (int j = 0; j < 8; ++j)
      s += ap[(size_t)((l * 8 + j) * 2 + 1) * 65536 + (size_t)(k0 + k) * 256 + (t0 + c)];
    lds[k][c] = s;
  }
  __syncthreads();
  #pragma unroll
  for (int i = 0; i < 16; ++i) {
    int tl = r + i * 4;
    QsumT[(size_t)l * 65536 + (size_t)(t0 + tl) * 256 + (k0 + c)] = lds[c][tl];
  }
}

// ---- k_zstage: grid 1024. Zin -> Zxbf (natural bf16), Zxt (transposed, m=2047 zeroed), zlab.
__global__ __launch_bounds__(256) void k_zstage(const float* __restrict__ Zin,
                                                short* __restrict__ Zxbf, short* __restrict__ Zxt,
                                                float* __restrict__ zlab) {
  __shared__ float lds[64][65];
  const int tb = blockIdx.x, tid = threadIdx.x;
  const int x = tb & 3, y = (tb >> 2) & 31, b = tb >> 7;
  const int k0 = x * 64, m0 = y * 64;
  const int c = tid & 63, r = tid >> 6;
  #pragma unroll
  for (int i = 0; i < 16; ++i) {
    int mrow = r + i * 4, m = m0 + mrow;
    float v = Zin[((size_t)b * NTOK + m) * NCH + k0 + c];
    lds[mrow][c] = v;
    Zxbf[((size_t)b * NTOK + m) * DD + k0 + c] = (short)f2b(v);
  }
  if (x == 0 && tid < 64) {
    int m = m0 + tid;
    zlab[b * NTOK + m] = (m == NVAL) ? 0.f : Zin[((size_t)b * NTOK + m) * NCH + DD];
  }
  __syncthreads();
  #pragma unroll
  for (int i = 0; i < 16; ++i) {
    int krow = r + i * 4;
    float v = lds[c][krow];
    if (m0 + c == NVAL) v = 0.f;
    Zxt[((size_t)b * DD + k0 + krow) * NTOK + m0 + c] = (short)f2b(v);
  }
}

// ---- k_gram: grid 1088. x<1024: b=x&7, tile=(x>>3)&15 (64x64), seg=x>>7 (K=256),
//      4 waves each 32x32 sub-tile -> fp32 partial Gacc[seg][b*16+t][4096].
//      x>=1024: gcol partials over 256-m segment via Zxbf (coalesced).
__global__ __launch_bounds__(256) void k_gram(const short* __restrict__ Zxt,
                                              const short* __restrict__ Zxbf,
                                              const float* __restrict__ zlab,
                                              float* __restrict__ Gacc,
                                              float* __restrict__ gcolacc) {
  __shared__ float zl[256];
  const int x = blockIdx.x, tid = threadIdx.x;
  if (x >= 1024) {
    const int idx = x - 1024, b = idx & 7, seg = idx >> 3;
    zl[tid] = zlab[b * NTOK + seg * 256 + tid];
    __syncthreads();
    const short* base = Zxbf + ((size_t)b * NTOK + seg * 256) * DD + tid;
    float s = 0.f;
    #pragma unroll 8
    for (int m = 0; m < 256; ++m) s += b2f(base[(size_t)m * DD]) * zl[m];
    gcolacc[(seg * 8 + b) * 256 + tid] = s;
    return;
  }
  const int lane = tid & 63, w = tid >> 6;
  const int b = x & 7, r = x >> 3, t = r & 15, seg = r >> 4;
  const int r0 = (t >> 2) * 64, c0 = (t & 3) * 64;
  const int ar = r0 + (w >> 1) * 32, bc = c0 + (w & 1) * 32;
  const short* A = Zxt + (size_t)b * DD * NTOK;
  f32x4 acc[2][2];
  #pragma unroll
  for (int f = 0; f < 2; ++f) for (int g = 0; g < 2; ++g) for (int i = 0; i < 4; ++i) acc[f][g][i] = 0.f;
  mm_tile_t<2, 2>(A, A, NTOK, NTOK, ar, bc, seg * 256, seg * 256 + 256, lane, acc);
  float* out = Gacc + ((size_t)seg * 128 + b * 16 + t) * 4096;
  #pragma unroll
  for (int f = 0; f < 2; ++f)
    #pragma unroll
    for (int g = 0; g < 2; ++g)
      #pragma unroll
      for (int i = 0; i < 4; ++i)
        out[((w >> 1) * 32 + f * 16 + ((lane >> 4) << 2) + i) * 64 +
            (w & 1) * 32 + g * 16 + (lane & 15)] = acc[f][g][i];
}

// ---- k_gred: grid 520. x<512: thread-linear 8-seg reduce -> Gbf. x>=512: gcol reduce.
__global__ __launch_bounds__(256) void k_gred(const float* __restrict__ Gacc,
                                              const float* __restrict__ gcolacc,
                                              short* __restrict__ Gbf, float* __restrict__ gcol) {
  const int x = blockIdx.x, tid = threadIdx.x;
  if (x >= 512) {
    const int b = x - 512;
    float s = 0.f;
    #pragma unroll
    for (int seg = 0; seg < 8; ++seg) s += gcolacc[(seg * 8 + b) * 256 + tid];
    gcol[b * 256 + tid] = s;
    return;
  }
  const int i0 = (x * 256 + tid) * 4;
  f32x4 s = {0.f, 0.f, 0.f, 0.f};
  #pragma unroll
  for (int seg = 0; seg < 8; ++seg) {
    f32x4 v = *(const f32x4*)(Gacc + (size_t)seg * 524288 + i0);
    #pragma unroll
    for (int i = 0; i < 4; ++i) s[i] += v[i];
  }
  const int b = i0 >> 16, rem = i0 & 65535;
  const int t = rem >> 12, rr = (rem >> 6) & 63, cc = rem & 63;
  const int row = (t >> 2) * 64 + rr, col = (t & 3) * 64 + cc;
  short4v o;
  #pragma unroll
  for (int i = 0; i < 4; ++i) o[i] = (short)f2b(s[i]);
  *(short4v*)(Gbf + (size_t)b * 65536 + (size_t)row * 256 + col) = o;
}

// ---- k_pv: grid 520. x<512: b=x&7, tile=x>>3: 64(t)x128(jc) of V = G Pcat^T,
//      4 waves each 32x64; write Vt3[b][c][j*256+t]. x>=512: mcol = invN*QsumT*gcol.
__global__ __launch_bounds__(256) void k_pv(const short* __restrict__ Gbf, const short* __restrict__ Pbf,
                                            const float* __restrict__ QsumT, const float* __restrict__ gcol,
                                            short* __restrict__ Vt3, float* __restrict__ mcol, int layer) {
  __shared__ float gs[256];
  const int x = blockIdx.x, tid = threadIdx.x;
  if (x >= 512) {
    const int b = x - 512;
    gs[tid] = gcol[b * 256 + tid];
    __syncthreads();
    float s = 0.f;
    for (int t = 0; t < 256; ++t) s += QsumT[(size_t)layer * 65536 + (size_t)t * 256 + tid] * gs[t];
    mcol[b * 256 + tid] = s * (1.0f / (float)NVAL);
    return;
  }
  const int lane = tid & 63, w = tid >> 6;
  const int b = x & 7, t = x >> 3;
  const int r0 = (t & 3) * 64, c0 = (t >> 2) * 128;
  const int ar = r0 + (w & 1) * 32, bc = c0 + (w >> 1) * 64;
  const short* A = Gbf + (size_t)b * 65536;
  const short* B = Pbf + (size_t)layer * 8 * 65536;
  f32x4 acc[2][4];
  #pragma unroll
  for (int f = 0; f < 2; ++f) for (int g = 0; g < 4; ++g) for (int i = 0; i < 4; ++i) acc[f][g][i] = 0.f;
  mm_tile_t<2, 4>(A, B, 256, 256, ar, bc, 0, 256, lane, acc);
  short* out = Vt3 + (size_t)b * 524288;
  #pragma unroll
  for (int f = 0; f < 2; ++f) {
    const int tt0 = ar + f * 16 + ((lane >> 4) << 2);
    #pragma unroll
    for (int g = 0; g < 4; ++g) {
      const int jc = bc + g * 16 + (lane & 15);
      const int j = jc >> 8, c = jc & 255;
      short4v p;
      #pragma unroll
      for (int i = 0; i < 4; ++i) p[i] = (short)f2b(acc[f][g][i]);
      *(short4v*)(out + (size_t)c * 2048 + j * 256 + tt0) = p;
    }
  }
}

// ---- k_qm: grid 1024. b=x&7, tile=(x>>3)&15 (64c x 64k of M^T), seg=x>>7 (K=256 of jt),
//      A'=Vt3[b] (c rows), B'=Qcat2[l] (k rows) -> fp32 partial Macc[seg][b*16+t][4096].
__global__ __launch_bounds__(256) void k_qm(const short* __restrict__ Vt3, const short* __restrict__ Qcat2,
                                            float* __restrict__ Macc, int layer) {
  const int x = blockIdx.x, tid = threadIdx.x;
  const int lane = tid & 63, w = tid >> 6;
  const int b = x & 7, r = x >> 3, t = r & 15, seg = r >> 4;
  const int c0 = (t >> 2) * 64, k0 = (t & 3) * 64;
  const int ar = c0 + (w >> 1) * 32, bc = k0 + (w & 1) * 32;
  const short* A = Vt3 + (size_t)b * 524288;
  const short* B = Qcat2 + (size_t)layer * 524288;
  f32x4 acc[2][2];
  #pragma unroll
  for (int f = 0; f < 2; ++f) for (int g = 0; g < 2; ++g) for (int i = 0; i < 4; ++i) acc[f][g][i] = 0.f;
  mm_tile_t<2, 2>(A, B, 2048, 2048, ar, bc, seg * 256, seg * 256 + 256, lane, acc);
  float* out = Macc + ((size_t)seg * 128 + b * 16 + t) * 4096;
  #pragma unroll
  for (int f = 0; f < 2; ++f)
    #pragma unroll
    for (int g = 0; g < 2; ++g)
      #pragma unroll
      for (int i = 0; i < 4; ++i)
        out[((w >> 1) * 32 + f * 16 + ((lane >> 4) << 2) + i) * 64 +
            (w & 1) * 32 + g * 16 + (lane & 15)] = acc[f][g][i];
}

// ---- k_mred: grid 512. thread-linear 8-seg reduce, *invN, -> Mt[b][c][k] bf16.
__global__ __launch_bounds__(256) void k_mred(const float* __restrict__ Macc, short* __restrict__ Mt) {
  const int x = blockIdx.x, tid = threadIdx.x;
  const int i0 = (x * 256 + tid) * 4;
  f32x4 s = {0.f, 0.f, 0.f, 0.f};
  #pragma unroll
  for (int seg = 0; seg < 8; ++seg) {
    f32x4 v = *(const f32x4*)(Macc + (size_t)seg * 524288 + i0);
    #pragma unroll
    for (int i = 0; i < 4; ++i) s[i] += v[i];
  }
  const float invN = 1.0f / (float)NVAL;
  const int b = i0 >> 16, rem = i0 & 65535;
  const int t = rem >> 12, rr = (rem >> 6) & 63, cc = rem & 63;
  const int row = (t >> 2) * 64 + rr, col = (t & 3) * 64 + cc;   // row=c-dim, col=k-dim
  short4v o;
  #pragma unroll
  for (int i = 0; i < 4; ++i) o[i] = (short)f2b(s[i] * invN);
  *(short4v*)(Mt + (size_t)b * 65536 + (size_t)row * 256 + col) = o;
}

// ---- k_apply: grid 512. b=x&7, tile=x>>3: 64n x 128c. Z = Zsrc + Zx M (+ label GEMV);
//      fused next-layer staging (Zxbf ping-pong, Zxt via LDS transpose, zlab).
__global__ __launch_bounds__(256) void k_apply(const float* __restrict__ Zsrc, float* __restrict__ Z,
                                               const short* __restrict__ Zxbf_in, const short* __restrict__ Mt,
                                               const float* __restrict__ mcol,
                                               short* __restrict__ Zxbf_out, short* __restrict__ Zxt_out,
                                               float* __restrict__ zlab_out, int wnext) {
  __shared__ short ldsT[128][66];
  const int tid = threadIdx.x, lane = tid & 63, w = tid >> 6;
  const int x = blockIdx.x;
  const int b = x & 7, t = x >> 3;
  const int n0 = (t >> 1) * 64, c0 = (t & 1) * 128;
  const int bc = c0 + w * 32;
  const short* A = Zxbf_in + (size_t)b * NTOK * DD;
  const short* B = Mt + (size_t)b * 65536;
  const bool gemv = (c0 == 0 && w == 0);
  f32x4 acc[4][2];
  #pragma unroll
  for (int f = 0; f < 4; ++f) for (int g = 0; g < 2; ++g) for (int i = 0; i < 4; ++i) acc[f][g][i] = 0.f;
  float s[4] = {0.f, 0.f, 0.f, 0.f};
  #pragma unroll 2
  for (int kk = 0; kk < 256; kk += 32) {
    const int kc = kk + ((lane >> 4) << 3);
    short8v av[4], bv[2];
    #pragma unroll
    for (int f = 0; f < 4; ++f)
      av[f] = *(const short8v*)(A + (size_t)(n0 + f * 16 + (lane & 15)) * DD + kc);
    #pragma unroll
    for (int g = 0; g < 2; ++g)
      bv[g] = *(const short8v*)(B + (size_t)(bc + g * 16 + (lane & 15)) * 256 + kc);
    if (gemv) {
      const float* mp = mcol + b * 256 + kc;
      f32x4 m0 = *(const f32x4*)mp, m1 = *(const f32x4*)(mp + 4);
      #pragma unroll
      for (int f = 0; f < 4; ++f) {
        #pragma unroll
        for (int q = 0; q < 4; ++q) {
          s[f] += b2f(av[f][q]) * m0[q];
          s[f] += b2f(av[f][4 + q]) * m1[q];
        }
      }
    }
    #pragma unroll
    for (int f = 0; f < 4; ++f)
      #pragma unroll
      for (int g = 0; g < 2; ++g)
        acc[f][g] = __builtin_amdgcn_mfma_f32_16x16x32_bf16(av[f], bv[g], acc[f][g], 0, 0, 0);
  }
  #pragma unroll
  for (int f = 0; f < 4; ++f) {
    const int nb = n0 + f * 16 + ((lane >> 4) << 2);
    #pragma unroll
    for (int g = 0; g < 2; ++g) {
      const int c = bc + g * 16 + (lane & 15);
      #pragma unroll
      for (int i = 0; i < 4; ++i) {
        size_t idx = ((size_t)b * NTOK + nb + i) * NCH + c;
        float nv = Zsrc[idx] + acc[f][g][i];
        Z[idx] = nv;
        unsigned short bvv = f2b(nv);
        if (wnext) {
          Zxbf_out[((size_t)b * NTOK + nb + i) * DD + c] = (short)bvv;
          ldsT[c - c0][nb - n0 + i] = (nb + i == NVAL) ? (short)0 : (short)bvv;
        }
      }
    }
  }
  if (gemv) {
    #pragma unroll
    for (int f = 0; f < 4; ++f) {
      float tt = s[f];
      tt += __shfl_xor(tt, 16);
      tt += __shfl_xor(tt, 32);
      if ((lane >> 4) == 0) {
        int n = n0 + f * 16 + (lane & 15);
        size_t idx = ((size_t)b * NTOK + n) * NCH + DD;
        float nv = Zsrc[idx] + tt;
        Z[idx] = nv;
        if (wnext) zlab_out[b * NTOK + n] = (n == NVAL) ? 0.f : nv;
      }
    }
  }
  if (wnext) {
    __syncthreads();
    const int cr = tid & 127, half = (tid >> 7) * 32;
    #pragma unroll
    for (int u = 0; u < 4; ++u) {
      short8v v = *(const short8v*)&ldsT[cr][half + u * 8];
      *(short8v*)(Zxt_out + ((size_t)b * DD + c0 + cr) * NTOK + n0 + half + u * 8) = v;
    }
  }
}

// ================= fallback (round-1 fp32 path, used if ws too small) =================
__global__ __launch_bounds__(256) void gram_kernel(const float* __restrict__ Z, float* __restrict__ G) {
  __shared__ float As[32][64];
  __shared__ float Bs[32][65];
  const int c0 = blockIdx.x * 64, k0 = blockIdx.y * 64, b = blockIdx.z;
  const int tid = threadIdx.x, tx = tid & 15, ty = tid >> 4;
  const float* Zb = Z + (size_t)b * NTOK * NCH;
  float acc[4][4] = {};
  for (int m0 = 0; m0 < NVAL; m0 += 32) {
    #pragma unroll
    for (int l = 0; l < 8; ++l) {
      int e = tid + l * 256, mm = e >> 6, kk = e & 63, m = m0 + mm;
      As[mm][kk] = (m < NVAL) ? Zb[(size_t)m * NCH + (k0 + kk)] : 0.f;
    }
    #pragma unroll
    for (int l = 0; l < 8; ++l) {
      int e = tid + l * 256, mm = e >> 6, cc = e & 63, m = m0 + mm, c = c0 + cc;
      Bs[mm][cc] = (m < NVAL && c < NCH) ? Zb[(size_t)m * NCH + c] : 0.f;
    }
    __syncthreads();
    #pragma unroll
    for (int mm = 0; mm < 32; ++mm) {
      float a[4], bb[4];
      #pragma unroll
      for (int i = 0; i < 4; ++i) a[i] = As[mm][ty * 4 + i];
      #pragma unroll
      for (int j = 0; j < 4; ++j) bb[j] = Bs[mm][tx * 4 + j];
      #pragma unroll
      for (int i = 0; i < 4; ++i)
        #pragma unroll
        for (int j = 0; j < 4; ++j) acc[i][j] += a[i] * bb[j];
    }
    __syncthreads();
  }
  float* Gb = G + (size_t)b * DD * NCH;
  #pragma unroll
  for (int i = 0; i < 4; ++i) {
    int k = k0 + ty * 4 + i;
    #pragma unroll
    for (int j = 0; j < 4; ++j) {
      int c = c0 + tx * 4 + j;
      if (c < NCH) Gb[(size_t)k * NCH + c] = acc[i][j];
    }
  }
}
__global__ __launch_bounds__(256) void pmul_kernel(const float* __restrict__ G, const float* __restrict__ allparam,
                                                   float* __restrict__ U, int layer, int j0, int JB) {
  __shared__ float As[64][33];
  __shared__ float Bs[64][33];
  const int c0 = blockIdx.x * 64, k0 = blockIdx.y * 64;
  const int b = blockIdx.z / JB, jj = blockIdx.z % JB, j = j0 + jj;
  const int tid = threadIdx.x, tx = tid & 15, ty = tid >> 4;
  const float* P = allparam + ((size_t)((layer * NH + j) * 2 + 0)) * DD * DD;
  const float* Gb = G + (size_t)b * DD * NCH;
  float acc[4][4] = {};
  for (int t0 = 0; t0 < DD; t0 += 32) {
    #pragma unroll
    for (int l = 0; l < 8; ++l) {
      int e = tid + l * 256, kk = e >> 5, tt = e & 31;
      As[kk][tt] = Gb[(size_t)(k0 + kk) * NCH + (t0 + tt)];
    }
    #pragma unroll
    for (int l = 0; l < 8; ++l) {
      int e = tid + l * 256, cc = e >> 5, tt = e & 31, c = c0 + cc;
      Bs[cc][tt] = (c < DD) ? P[(size_t)c * DD + (t0 + tt)] : 0.f;
    }
    __syncthreads();
    #pragma unroll
    for (int tt = 0; tt < 32; ++tt) {
      float a[4], bb[4];
      #pragma unroll
      for (int i = 0; i < 4; ++i) a[i] = As[ty * 4 + i][tt];
      #pragma unroll
      for (int j2 = 0; j2 < 4; ++j2) bb[j2] = Bs[tx * 4 + j2][tt];
      #pragma unroll
      for (int i = 0; i < 4; ++i)
        #pragma unroll
        for (int j2 = 0; j2 < 4; ++j2) acc[i][j2] += a[i] * bb[j2];
    }
    __syncthreads();
  }
  float* Us = U + ((size_t)(b * JB + jj)) * DD * NCH;
  #pragma unroll
  for (int i = 0; i < 4; ++i) {
    int k = k0 + ty * 4 + i;
    #pragma unroll
    for (int j2 = 0; j2 < 4; ++j2) {
      int c = c0 + tx * 4 + j2;
      if (c < DD)       Us[(size_t)k * NCH + c] = acc[i][j2];
      else if (c == DD) Us[(size_t)k * NCH + c] = Gb[(size_t)k * NCH + DD];
    }
  }
}
__global__ __launch_bounds__(256) void qmul_kernel(const float* __restrict__ U, const float* __restrict__ allparam,
                                                   float* __restrict__ M, int layer, int j0, int jcount, int JB,
                                                   int accumulate) {
  __shared__ float As[64][33];
  __shared__ float Bs[32][65];
  const int c0 = blockIdx.x * 64, k0 = blockIdx.y * 64, b = blockIdx.z;
  const int tid = threadIdx.x, tx = tid & 15, ty = tid >> 4;
  const float invN = 1.0f / (float)NVAL;
  float acc[4][4] = {};
  for (int jj = 0; jj < jcount; ++jj) {
    const float* Q = allparam + ((size_t)((layer * NH + (j0 + jj)) * 2 + 1)) * DD * DD;
    const float* Ub = U + ((size_t)(b * JB + jj)) * DD * NCH;
    for (int t0 = 0; t0 < DD; t0 += 32) {
      #pragma unroll
      for (int l = 0; l < 8; ++l) {
        int e = tid + l * 256, kk = e >> 5, tt = e & 31;
        As[kk][tt] = Q[(size_t)(k0 + kk) * DD + (t0 + tt)];
      }
      #pragma unroll
      for (int l = 0; l < 8; ++l) {
        int e = tid + l * 256, tt = e >> 6, cc = e & 63, c = c0 + cc;
        Bs[tt][cc] = (c < NCH) ? Ub[(size_t)(t0 + tt) * NCH + c] : 0.f;
      }
      __syncthreads();
      #pragma unroll
      for (int tt = 0; tt < 32; ++tt) {
        float a[4], bb[4];
        #pragma unroll
        for (int i = 0; i < 4; ++i) a[i] = As[ty * 4 + i][tt];
        #pragma unroll
        for (int j2 = 0; j2 < 4; ++j2) bb[j2] = Bs[tt][tx * 4 + j2];
        #pragma unroll
        for (int i = 0; i < 4; ++i)
          #pragma unroll
          for (int j2 = 0; j2 < 4; ++j2) acc[i][j2] += a[i] * bb[j2];
      }
      __syncthreads();
    }
  }
  #pragma unroll
  for (int i = 0; i < 4; ++i) {
    int k = k0 + ty * 4 + i;
    #pragma unroll
    for (int j2 = 0; j2 < 4; ++j2) {
      int c = c0 + tx * 4 + j2;
      if (c < NCH) {
        size_t idx = ((size_t)b * DD + k) * NCH + c;
        float v = invN * acc[i][j2];
        M[idx] = accumulate ? (M[idx] + v) : v;
      }
    }
  }
}
__global__ __launch_bounds__(256) void apply_kernel(float* __restrict__ Z, const float* __restrict__ M) {
  __shared__ float Zs[8][256];
  const int b = blockIdx.y, n0 = blockIdx.x * 8;
  float* Zb = Z + (size_t)b * NTOK * NCH;
  const float* Mb = M + (size_t)b * DD * NCH;
  const int tid = threadIdx.x;
  #pragma unroll
  for (int l = 0; l < 8; ++l) {
    int e = tid + l * 256, r = e >> 8, k = e & 255;
    Zs[r][k] = Zb[(size_t)(n0 + r) * NCH + k];
  }
  __syncthreads();
  const int r = tid >> 5, cbase = tid & 31;
  float acc[9] = {};
  #pragma unroll 4
  for (int k = 0; k < 256; ++k) {
    float z = Zs[r][k];
    const float* Mrow = Mb + (size_t)k * NCH;
    #pragma unroll
    for (int ii = 0; ii < 8; ++ii) acc[ii] += z * Mrow[cbase + ii * 32];
    if (cbase == 0) acc[8] += z * Mrow[256];
  }
  #pragma unroll
  for (int ii = 0; ii < 8; ++ii)
    Zb[(size_t)(n0 + r) * NCH + cbase + ii * 32] += acc[ii];
  if (cbase == 0) Zb[(size_t)(n0 + r) * NCH + 256] += acc[8];
}

// =====================================================================================
extern "C" void kernel_launch(void* const* d_in, const int* in_sizes, int n_in,
                              void* d_out, int out_size, void* d_ws, size_t ws_size,
                              hipStream_t stream) {
  const float* Zin      = (const float*)d_in[0];
  const float* allparam = (const float*)d_in[1];
  float* Z = (float*)d_out;

  // ws layout (bytes)
  const size_t o_zx0  = 0;                         // bf16 [8][2048][256]   8,388,608 (ping)
  const size_t o_zx1  = o_zx0  + 8388608;          // bf16                  8,388,608 (pong)
  const size_t o_zxt  = o_zx1  + 8388608;          // bf16 [8][256][2048]   8,388,608
  const size_t o_acc  = o_zxt  + 8388608;          // f32  [8][128][4096]   16,777,216 (Gacc/Macc alias)
  const size_t o_gbf  = o_acc  + 16777216;         // bf16 [8][256][256]    1,048,576
  const size_t o_vt   = o_gbf  + 1048576;          // bf16 [8][256][2048]   8,388,608 (Vt3)
  const size_t o_mt   = o_vt   + 8388608;          // bf16 [8][256][256]    1,048,576
  const size_t o_pbf  = o_mt   + 1048576;          // bf16 [4][8][256][256] 4,194,304
  const size_t o_qc2  = o_pbf  + 4194304;          // bf16 [4][256][2048]   4,194,304 (Qcat2)
  const size_t o_qsum = o_qc2  + 4194304;          // f32  [4][256][256]    1,048,576
  const size_t o_gca  = o_qsum + 1048576;          // f32  [8][8][256]      65,536 (gcolacc)
  const size_t o_gcol = o_gca  + 65536;            // f32  [8][256]         8,192
  const size_t o_mcol = o_gcol + 8192;             // f32  [8][256]         8,192
  const size_t o_zlab = o_mcol + 8192;             // f32  [8][2048]        65,536
  const size_t NEED   = o_zlab + 65536;

  if (ws_size >= NEED) {
    char* wsb = (char*)d_ws;
    short* Zx[2]   = { (short*)(wsb + o_zx0), (short*)(wsb + o_zx1) };
    short* Zxt     = (short*)(wsb + o_zxt);
    float* Acc     = (float*)(wsb + o_acc);         // Gacc, then Macc (dead after gred)
    short* Gbf     = (short*)(wsb + o_gbf);
    short* Vt3     = (short*)(wsb + o_vt);
    short* Mt      = (short*)(wsb + o_mt);
    short* Pbf     = (short*)(wsb + o_pbf);
    short* Qcat2   = (short*)(wsb + o_qc2);
    float* QsumT   = (float*)(wsb + o_qsum);
    float* gcolacc = (float*)(wsb + o_gca);
    float* gcol    = (float*)(wsb + o_gcol);
    float* mcol    = (float*)(wsb + o_mcol);
    float* zlab    = (float*)(wsb + o_zlab);

    k_prep<<<dim3(2112), dim3(256), 0, stream>>>(allparam, Pbf, Qcat2, QsumT);
    k_zstage<<<dim3(1024), dim3(256), 0, stream>>>(Zin, Zx[0], Zxt, zlab);

    for (int layer = 0; layer < NL; ++layer) {
      const int cur = layer & 1;
      const int wnext = (layer < NL - 1) ? 1 : 0;
      const float* Zsrc = (layer == 0) ? Zin : Z;
      k_gram<<<dim3(1088), dim3(256), 0, stream>>>(Zxt, Zx[cur], zlab, Acc, gcolacc);
      k_gred<<<dim3(520), dim3(256), 0, stream>>>(Acc, gcolacc, Gbf, gcol);
      k_pv<<<dim3(520), dim3(256), 0, stream>>>(Gbf, Pbf, QsumT, gcol, Vt3, mcol, layer);
      k_qm<<<dim3(1024), dim3(256), 0, stream>>>(Vt3, Qcat2, Acc, layer);
      k_mred<<<dim3(512), dim3(256), 0, stream>>>(Acc, Mt);
      k_apply<<<dim3(512), dim3(256), 0, stream>>>(Zsrc, Z, Zx[cur], Mt, mcol,
                                                   Zx[cur ^ 1], Zxt, zlab, wnext);
    }
    return;
  }

  // -------- fallback: round-1 fp32 path --------
  const size_t zbytes = (size_t)NB * NTOK * NCH * sizeof(float);
  hipMemcpyAsync(Z, Zin, zbytes, hipMemcpyDeviceToDevice, stream);
  const size_t Gn = (size_t)NB * DD * NCH;
  float* ws   = (float*)d_ws;
  float* Gbuf = ws;
  float* Mbuf = ws + Gn;
  float* Ubuf = ws + 2 * Gn;
  const int JB = (ws_size >= (size_t)(2 + 8) * Gn * sizeof(float)) ? 8 : 1;
  dim3 blk(256);
  for (int layer = 0; layer < NL; ++layer) {
    gram_kernel<<<dim3(5, 4, NB), blk, 0, stream>>>(Z, Gbuf);
    for (int j0 = 0; j0 < NH; j0 += JB) {
      pmul_kernel<<<dim3(5, 4, NB * JB), blk, 0, stream>>>(Gbuf, allparam, Ubuf, layer, j0, JB);
      qmul_kernel<<<dim3(5, 4, NB), blk, 0, stream>>>(Ubuf, allparam, Mbuf, layer, j0, JB, JB,
                                                      (j0 == 0) ? 0 : 1);
    }
    apply_kernel<<<dim3(NTOK / 8, NB), blk, 0, stream>>>(Z, Mbuf);
  }
}